// Round 1
// baseline (2151.421 us; speedup 1.0000x reference)
//
#include <hip/hip_runtime.h>

// ---------------------------------------------------------------------------
// EncodedGCN: x[N,8] + scalar s-encoder column -> GCNConv(9->32) -> lrelu ->
// GCNConv(32->16) -> lrelu -> fc(16->1).
// Strategy: aggregate BEFORE the linear for conv1 (9 dims), AFTER the linear
// for conv2 (16 dims). Scatter-add via fp32 global atomics (L2-resident dst).
// ---------------------------------------------------------------------------

__global__ void k_senc(const float* __restrict__ sv, const float* __restrict__ w1,
                       const float* __restrict__ b1, const float* __restrict__ w2,
                       const float* __restrict__ b2, float* __restrict__ senc) {
    __shared__ float hid[32];
    int j = threadIdx.x;
    if (j < 32) {
        float acc = b1[j];
        #pragma unroll 8
        for (int k = 0; k < 64; ++k) acc += sv[k] * w1[k * 32 + j];
        hid[j] = acc > 0.f ? acc : 0.f;
    }
    __syncthreads();
    if (j == 0) {
        float acc = b2[0];
        #pragma unroll 8
        for (int k = 0; k < 32; ++k) acc += hid[k] * w2[k];
        senc[0] = acc;
    }
}

__global__ void k_deg_init(float* __restrict__ deg, int n) {
    int i = blockIdx.x * blockDim.x + threadIdx.x;
    if (i < n) deg[i] = 1.0f;  // self-loop weight
}

__global__ void k_deg_edges(const int* __restrict__ ei, const float* __restrict__ ew,
                            float* __restrict__ deg, int E) {
    int e = blockIdx.x * blockDim.x + threadIdx.x;
    if (e < E) atomicAdd(&deg[ei[E + e]], ew[e]);
}

// dinv = rsqrt(deg) in-place; init agg9[i][:] = dinv^2 * [x[i][0..7], senc]
__global__ void k_dinv_agginit(float* __restrict__ dinv, const float* __restrict__ x,
                               const float* __restrict__ senc, float* __restrict__ agg9,
                               int n) {
    int i = blockIdx.x * blockDim.x + threadIdx.x;
    if (i >= n) return;
    float d = dinv[i];
    float di = d > 0.f ? rsqrtf(d) : 0.f;
    dinv[i] = di;
    float d2 = di * di;
    const float4* xr = reinterpret_cast<const float4*>(x + (size_t)i * 8);
    float4 u = xr[0], v = xr[1];
    float* dst = agg9 + (size_t)i * 9;
    dst[0] = d2 * u.x; dst[1] = d2 * u.y; dst[2] = d2 * u.z; dst[3] = d2 * u.w;
    dst[4] = d2 * v.x; dst[5] = d2 * v.y; dst[6] = d2 * v.z; dst[7] = d2 * v.w;
    dst[8] = d2 * senc[0];
}

__global__ void k_agg1(const int* __restrict__ ei, const float* __restrict__ ew,
                       const float* __restrict__ dinv, const float* __restrict__ x,
                       const float* __restrict__ senc, float* __restrict__ agg9,
                       int E) {
    int e = blockIdx.x * blockDim.x + threadIdx.x;
    if (e >= E) return;
    int r = ei[e], c = ei[E + e];
    float nrm = dinv[r] * ew[e] * dinv[c];
    const float4* xr = reinterpret_cast<const float4*>(x + (size_t)r * 8);
    float4 u = xr[0], v = xr[1];
    float* dst = agg9 + (size_t)c * 9;
    atomicAdd(dst + 0, nrm * u.x);
    atomicAdd(dst + 1, nrm * u.y);
    atomicAdd(dst + 2, nrm * u.z);
    atomicAdd(dst + 3, nrm * u.w);
    atomicAdd(dst + 4, nrm * v.x);
    atomicAdd(dst + 5, nrm * v.y);
    atomicAdd(dst + 6, nrm * v.z);
    atomicAdd(dst + 7, nrm * v.w);
    atomicAdd(dst + 8, nrm * senc[0]);
}

// pre1 = agg9 @ W1 + b1 ; h1 = lrelu(pre1) ; t = h1 @ W2 ; agg2init = dinv^2*t
__global__ void k_node1(const float* __restrict__ agg9, const float* __restrict__ dinv,
                        const float* __restrict__ W1, const float* __restrict__ b1,
                        const float* __restrict__ W2,
                        float* __restrict__ t, float* __restrict__ agg2, int n) {
    __shared__ float sW1[288];
    __shared__ float sb1[32];
    __shared__ float sW2[512];
    for (int k = threadIdx.x; k < 288; k += blockDim.x) sW1[k] = W1[k];
    for (int k = threadIdx.x; k < 512; k += blockDim.x) sW2[k] = W2[k];
    if (threadIdx.x < 32) sb1[threadIdx.x] = b1[threadIdx.x];
    __syncthreads();
    int i = blockIdx.x * blockDim.x + threadIdx.x;
    if (i >= n) return;
    float a[9];
    #pragma unroll
    for (int k = 0; k < 9; ++k) a[k] = agg9[(size_t)i * 9 + k];
    float h[32];
    #pragma unroll
    for (int j = 0; j < 32; ++j) {
        float acc = sb1[j];
        #pragma unroll
        for (int k = 0; k < 9; ++k) acc += a[k] * sW1[k * 32 + j];
        h[j] = acc > 0.f ? acc : 0.01f * acc;
    }
    float di = dinv[i];
    float d2 = di * di;
    #pragma unroll
    for (int q = 0; q < 16; ++q) {
        float acc = 0.f;
        #pragma unroll
        for (int j = 0; j < 32; ++j) acc += h[j] * sW2[j * 16 + q];
        t[(size_t)i * 16 + q] = acc;
        agg2[(size_t)i * 16 + q] = d2 * acc;
    }
}

__global__ void k_agg2(const int* __restrict__ ei, const float* __restrict__ ew,
                       const float* __restrict__ dinv, const float* __restrict__ t,
                       float* __restrict__ agg2, int E) {
    int e = blockIdx.x * blockDim.x + threadIdx.x;
    if (e >= E) return;
    int r = ei[e], c = ei[E + e];
    float nrm = dinv[r] * ew[e] * dinv[c];
    const float4* tr = reinterpret_cast<const float4*>(t + (size_t)r * 16);
    float4 u0 = tr[0], u1 = tr[1], u2 = tr[2], u3 = tr[3];
    float* dst = agg2 + (size_t)c * 16;
    atomicAdd(dst + 0,  nrm * u0.x);
    atomicAdd(dst + 1,  nrm * u0.y);
    atomicAdd(dst + 2,  nrm * u0.z);
    atomicAdd(dst + 3,  nrm * u0.w);
    atomicAdd(dst + 4,  nrm * u1.x);
    atomicAdd(dst + 5,  nrm * u1.y);
    atomicAdd(dst + 6,  nrm * u1.z);
    atomicAdd(dst + 7,  nrm * u1.w);
    atomicAdd(dst + 8,  nrm * u2.x);
    atomicAdd(dst + 9,  nrm * u2.y);
    atomicAdd(dst + 10, nrm * u2.z);
    atomicAdd(dst + 11, nrm * u2.w);
    atomicAdd(dst + 12, nrm * u3.x);
    atomicAdd(dst + 13, nrm * u3.y);
    atomicAdd(dst + 14, nrm * u3.z);
    atomicAdd(dst + 15, nrm * u3.w);
}

__global__ void k_final(const float* __restrict__ agg2, const float* __restrict__ b2,
                        const float* __restrict__ fw, const float* __restrict__ fb,
                        float* __restrict__ out, int n) {
    __shared__ float sb2[16];
    __shared__ float sfw[16];
    if (threadIdx.x < 16) { sb2[threadIdx.x] = b2[threadIdx.x]; sfw[threadIdx.x] = fw[threadIdx.x]; }
    __syncthreads();
    int i = blockIdx.x * blockDim.x + threadIdx.x;
    if (i >= n) return;
    float acc = fb[0];
    #pragma unroll
    for (int k = 0; k < 16; ++k) {
        float v = agg2[(size_t)i * 16 + k] + sb2[k];
        v = v > 0.f ? v : 0.01f * v;
        acc += v * sfw[k];
    }
    out[i] = acc;
}

extern "C" void kernel_launch(void* const* d_in, const int* in_sizes, int n_in,
                              void* d_out, int out_size, void* d_ws, size_t ws_size,
                              hipStream_t stream) {
    const float* x      = (const float*)d_in[0];
    const int*   ei     = (const int*)d_in[1];
    const float* ew     = (const float*)d_in[2];
    const float* sv     = (const float*)d_in[3];
    const float* sfc1w  = (const float*)d_in[4];
    const float* sfc1b  = (const float*)d_in[5];
    const float* sfc2w  = (const float*)d_in[6];
    const float* sfc2b  = (const float*)d_in[7];
    const float* conv1w = (const float*)d_in[8];
    const float* conv1b = (const float*)d_in[9];
    const float* conv2w = (const float*)d_in[10];
    const float* conv2b = (const float*)d_in[11];
    const float* fc1w   = (const float*)d_in[12];
    const float* fc1b   = (const float*)d_in[13];

    const int n = in_sizes[0] / 8;
    const int E = in_sizes[2];

    float* ws    = (float*)d_ws;
    float* senc  = ws;                    // [4] (1 used)
    float* dinv  = ws + 4;                // [n]  (deg, then dinv in-place)
    float* agg9  = dinv + n;              // [9n]
    float* tbuf  = agg9 + (size_t)9 * n;  // [16n]
    float* agg2  = tbuf + (size_t)16 * n; // [16n]

    const int BT = 256;
    const int gN = (n + BT - 1) / BT;
    const int gE = (E + BT - 1) / BT;

    k_senc<<<1, 64, 0, stream>>>(sv, sfc1w, sfc1b, sfc2w, sfc2b, senc);
    k_deg_init<<<gN, BT, 0, stream>>>(dinv, n);
    k_deg_edges<<<gE, BT, 0, stream>>>(ei, ew, dinv, E);
    k_dinv_agginit<<<gN, BT, 0, stream>>>(dinv, x, senc, agg9, n);
    k_agg1<<<gE, BT, 0, stream>>>(ei, ew, dinv, x, senc, agg9, E);
    k_node1<<<gN, BT, 0, stream>>>(agg9, dinv, conv1w, conv1b, conv2w, tbuf, agg2, n);
    k_agg2<<<gE, BT, 0, stream>>>(ei, ew, dinv, tbuf, agg2, E);
    k_final<<<gN, BT, 0, stream>>>(agg2, conv2b, fc1w, fc1b, (float*)d_out, n);
}

// Round 2
// 310.966 us; speedup vs baseline: 6.9185x; 6.9185x over previous
//
#include <hip/hip_runtime.h>

// ---------------------------------------------------------------------------
// EncodedGCN, round 1: replace float atomic scatter (write-through to HBM,
// 32B/atomic -> 1.25GB of writes) with device-built CSR + gather aggregation.
// Pipeline: senc -> count(in-deg) -> scan -> fill CSR -> deg/dinv gather ->
// pass1 (agg9 gather + W1 + lrelu + W2 -> t, store nrm back into CSR) ->
// pass2 (agg16 gather + b2 + lrelu + fc -> out).
// ---------------------------------------------------------------------------

__global__ void k_senc(const float* __restrict__ sv, const float* __restrict__ w1,
                       const float* __restrict__ b1, const float* __restrict__ w2,
                       const float* __restrict__ b2, float* __restrict__ senc) {
    __shared__ float hid[32];
    int j = threadIdx.x;
    if (j < 32) {
        float acc = b1[j];
        #pragma unroll 8
        for (int k = 0; k < 64; ++k) acc += sv[k] * w1[k * 32 + j];
        hid[j] = acc > 0.f ? acc : 0.f;
    }
    __syncthreads();
    if (j == 0) {
        float acc = b2[0];
        #pragma unroll 8
        for (int k = 0; k < 32; ++k) acc += hid[k] * w2[k];
        senc[0] = acc;
    }
}

__global__ void k_count(const int* __restrict__ ei, int* __restrict__ cnt, int E) {
    int e = blockIdx.x * blockDim.x + threadIdx.x;
    if (e < E) atomicAdd(&cnt[ei[E + e]], 1);
}

// exclusive scan, 3 kernels. scan1: per-256-block scan; scan2: block sums
// (single block, up to 512 entries); scan3: add offsets, write row & cursor.
__global__ void k_scan1(const int* __restrict__ cnt, int* __restrict__ row,
                        int* __restrict__ bsum, int n) {
    __shared__ int s[256];
    int i = blockIdx.x * 256 + threadIdx.x;
    int v = (i < n) ? cnt[i] : 0;
    s[threadIdx.x] = v;
    __syncthreads();
    for (int off = 1; off < 256; off <<= 1) {
        int tv = (threadIdx.x >= off) ? s[threadIdx.x - off] : 0;
        __syncthreads();
        if (threadIdx.x >= off) s[threadIdx.x] += tv;
        __syncthreads();
    }
    if (i < n) row[i] = s[threadIdx.x] - v;   // exclusive
    if (threadIdx.x == 255) bsum[blockIdx.x] = s[255];
}

__global__ void k_scan2(int* __restrict__ bsum, int nb) {
    __shared__ int s[512];
    int v = (threadIdx.x < nb) ? bsum[threadIdx.x] : 0;
    s[threadIdx.x] = v;
    __syncthreads();
    for (int off = 1; off < 512; off <<= 1) {
        int tv = (threadIdx.x >= off) ? s[threadIdx.x - off] : 0;
        __syncthreads();
        if (threadIdx.x >= off) s[threadIdx.x] += tv;
        __syncthreads();
    }
    if (threadIdx.x < nb) bsum[threadIdx.x] = s[threadIdx.x] - v;  // exclusive
}

__global__ void k_scan3(int* __restrict__ row, const int* __restrict__ bsum,
                        int* __restrict__ cursor, int n, int E) {
    int i = blockIdx.x * blockDim.x + threadIdx.x;
    if (i < n) {
        int v = row[i] + bsum[i >> 8];
        row[i] = v;
        cursor[i] = v;
    }
    if (i == 0) row[n] = E;
}

__global__ void k_fill(const int* __restrict__ ei, const float* __restrict__ ew,
                       int* __restrict__ cursor, int* __restrict__ csr_src,
                       float* __restrict__ csr_w, int E) {
    int e = blockIdx.x * blockDim.x + threadIdx.x;
    if (e >= E) return;
    int c = ei[E + e];
    int pos = atomicAdd(&cursor[c], 1);
    csr_src[pos] = ei[e];
    csr_w[pos] = ew[e];
}

__global__ void k_dinv(const int* __restrict__ row, const float* __restrict__ csr_w,
                       float* __restrict__ dinv, int n) {
    int i = blockIdx.x * blockDim.x + threadIdx.x;
    if (i >= n) return;
    int s0 = row[i], s1 = row[i + 1];
    float d = 1.0f;  // self-loop
    for (int s = s0; s < s1; ++s) d += csr_w[s];
    dinv[i] = rsqrtf(d);
}

// agg9 gather + conv1 + lrelu + conv2 -> t[i][16]; store nrm back into csr_w.
__global__ void k_pass1(const int* __restrict__ row, const int* __restrict__ src,
                        float* __restrict__ warr, const float* __restrict__ dinv,
                        const float* __restrict__ x, const float* __restrict__ senc,
                        const float* __restrict__ W1, const float* __restrict__ b1,
                        const float* __restrict__ W2, float* __restrict__ t, int n) {
    __shared__ float sW1[288];
    __shared__ float sb1[32];
    __shared__ float sW2[512];
    for (int k = threadIdx.x; k < 288; k += blockDim.x) sW1[k] = W1[k];
    for (int k = threadIdx.x; k < 512; k += blockDim.x) sW2[k] = W2[k];
    if (threadIdx.x < 32) sb1[threadIdx.x] = b1[threadIdx.x];
    __syncthreads();
    int i = blockIdx.x * blockDim.x + threadIdx.x;
    if (i >= n) return;
    float di = dinv[i];
    float d2 = di * di;
    float se = senc[0];
    float a[8];
    const float4* xi = reinterpret_cast<const float4*>(x + (size_t)i * 8);
    float4 u = xi[0], v = xi[1];
    a[0] = d2 * u.x; a[1] = d2 * u.y; a[2] = d2 * u.z; a[3] = d2 * u.w;
    a[4] = d2 * v.x; a[5] = d2 * v.y; a[6] = d2 * v.z; a[7] = d2 * v.w;
    float wsum = d2;  // coefficient of senc column
    int s0 = row[i], s1 = row[i + 1];
    for (int s = s0; s < s1; ++s) {
        int r = src[s];
        float nrm = dinv[r] * warr[s] * di;
        warr[s] = nrm;  // reuse in pass2
        const float4* xr = reinterpret_cast<const float4*>(x + (size_t)r * 8);
        float4 p = xr[0], q = xr[1];
        a[0] += nrm * p.x; a[1] += nrm * p.y; a[2] += nrm * p.z; a[3] += nrm * p.w;
        a[4] += nrm * q.x; a[5] += nrm * q.y; a[6] += nrm * q.z; a[7] += nrm * q.w;
        wsum += nrm;
    }
    float a8 = wsum * se;
    float h[32];
    #pragma unroll
    for (int j = 0; j < 32; ++j) {
        float acc = sb1[j] + a8 * sW1[8 * 32 + j];
        #pragma unroll
        for (int k = 0; k < 8; ++k) acc += a[k] * sW1[k * 32 + j];
        h[j] = acc > 0.f ? acc : 0.01f * acc;
    }
    float* ti = t + (size_t)i * 16;
    #pragma unroll
    for (int q2 = 0; q2 < 16; ++q2) {
        float acc = 0.f;
        #pragma unroll
        for (int j = 0; j < 32; ++j) acc += h[j] * sW2[j * 16 + q2];
        ti[q2] = acc;
    }
}

// agg16 gather + b2 + lrelu + fc -> out
__global__ void k_pass2(const int* __restrict__ row, const int* __restrict__ src,
                        const float* __restrict__ wnrm, const float* __restrict__ dinv,
                        const float* __restrict__ t, const float* __restrict__ b2,
                        const float* __restrict__ fw, const float* __restrict__ fb,
                        float* __restrict__ out, int n) {
    __shared__ float sb2[16];
    __shared__ float sfw[16];
    if (threadIdx.x < 16) { sb2[threadIdx.x] = b2[threadIdx.x]; sfw[threadIdx.x] = fw[threadIdx.x]; }
    __syncthreads();
    int i = blockIdx.x * blockDim.x + threadIdx.x;
    if (i >= n) return;
    float di = dinv[i];
    float d2 = di * di;
    float acc[16];
    const float4* ti = reinterpret_cast<const float4*>(t + (size_t)i * 16);
    #pragma unroll
    for (int q = 0; q < 4; ++q) {
        float4 u = ti[q];
        acc[4 * q + 0] = d2 * u.x; acc[4 * q + 1] = d2 * u.y;
        acc[4 * q + 2] = d2 * u.z; acc[4 * q + 3] = d2 * u.w;
    }
    int s0 = row[i], s1 = row[i + 1];
    for (int s = s0; s < s1; ++s) {
        int r = src[s];
        float nrm = wnrm[s];
        const float4* tr = reinterpret_cast<const float4*>(t + (size_t)r * 16);
        #pragma unroll
        for (int q = 0; q < 4; ++q) {
            float4 u = tr[q];
            acc[4 * q + 0] += nrm * u.x; acc[4 * q + 1] += nrm * u.y;
            acc[4 * q + 2] += nrm * u.z; acc[4 * q + 3] += nrm * u.w;
        }
    }
    float o = fb[0];
    #pragma unroll
    for (int k = 0; k < 16; ++k) {
        float v = acc[k] + sb2[k];
        v = v > 0.f ? v : 0.01f * v;
        o += v * sfw[k];
    }
    out[i] = o;
}

extern "C" void kernel_launch(void* const* d_in, const int* in_sizes, int n_in,
                              void* d_out, int out_size, void* d_ws, size_t ws_size,
                              hipStream_t stream) {
    const float* x      = (const float*)d_in[0];
    const int*   ei     = (const int*)d_in[1];
    const float* ew     = (const float*)d_in[2];
    const float* sv     = (const float*)d_in[3];
    const float* sfc1w  = (const float*)d_in[4];
    const float* sfc1b  = (const float*)d_in[5];
    const float* sfc2w  = (const float*)d_in[6];
    const float* sfc2b  = (const float*)d_in[7];
    const float* conv1w = (const float*)d_in[8];
    const float* conv1b = (const float*)d_in[9];
    const float* conv2w = (const float*)d_in[10];
    const float* conv2b = (const float*)d_in[11];
    const float* fc1w   = (const float*)d_in[12];
    const float* fc1b   = (const float*)d_in[13];

    const int n = in_sizes[0] / 8;
    const int E = in_sizes[2];

    // workspace layout (4-byte words, each segment aligned to 16B)
    size_t off = 0;
    auto alloc = [&](size_t words) { size_t o = off; off += (words + 3) & ~(size_t)3; return o; };
    float* base   = (float*)d_ws;
    float* senc   = base + alloc(4);
    float* dinv   = base + alloc(n);
    int*   rowp   = (int*)(base + alloc(n + 1));
    int*   cnt    = (int*)(base + alloc(n));      // reused as cursor
    int*   bsum   = (int*)(base + alloc(1024));
    int*   csrsrc = (int*)(base + alloc(E));
    float* csrw   = base + alloc(E);
    float* tbuf   = base + alloc((size_t)16 * n);

    const int BT = 256;
    const int gN = (n + BT - 1) / BT;
    const int gE = (E + BT - 1) / BT;
    const int nb = gN;  // number of scan1 blocks (must be <= 512)

    k_senc<<<1, 64, 0, stream>>>(sv, sfc1w, sfc1b, sfc2w, sfc2b, senc);
    hipMemsetAsync(cnt, 0, (size_t)n * 4, stream);
    k_count<<<gE, BT, 0, stream>>>(ei, cnt, E);
    k_scan1<<<nb, 256, 0, stream>>>(cnt, rowp, bsum, n);
    k_scan2<<<1, 512, 0, stream>>>(bsum, nb);
    k_scan3<<<gN, BT, 0, stream>>>(rowp, bsum, cnt, n, E);  // cnt becomes cursor
    k_fill<<<gE, BT, 0, stream>>>(ei, ew, cnt, csrsrc, csrw, E);
    k_dinv<<<gN, BT, 0, stream>>>(rowp, csrw, dinv, n);
    k_pass1<<<gN, BT, 0, stream>>>(rowp, csrsrc, csrw, dinv, x, senc,
                                   conv1w, conv1b, conv2w, tbuf, n);
    k_pass2<<<gN, BT, 0, stream>>>(rowp, csrsrc, csrw, dinv, tbuf,
                                   conv2b, fc1w, fc1b, (float*)d_out, n);
}

// Round 3
// 227.548 us; speedup vs baseline: 9.4548x; 1.3666x over previous
//
#include <hip/hip_runtime.h>

// ---------------------------------------------------------------------------
// EncodedGCN, round 2: CSR build without fill-atomics.
// k_count's atomicAdd return value IS the per-edge rank within its dest ->
// store rank (coalesced), then fill computes pos = row[dest]+rank (no atomic)
// and writes ONE packed 8B {src, w} entry per edge (half the dirty lines).
// ---------------------------------------------------------------------------

__global__ void k_senc(const float* __restrict__ sv, const float* __restrict__ w1,
                       const float* __restrict__ b1, const float* __restrict__ w2,
                       const float* __restrict__ b2, float* __restrict__ senc) {
    __shared__ float hid[32];
    int j = threadIdx.x;
    if (j < 32) {
        float acc = b1[j];
        #pragma unroll 8
        for (int k = 0; k < 64; ++k) acc += sv[k] * w1[k * 32 + j];
        hid[j] = acc > 0.f ? acc : 0.f;
    }
    __syncthreads();
    if (j == 0) {
        float acc = b2[0];
        #pragma unroll 8
        for (int k = 0; k < 32; ++k) acc += hid[k] * w2[k];
        senc[0] = acc;
    }
}

// rank[e] = old count of dest  (atomic returns order index)
__global__ void k_count(const int* __restrict__ ei, int* __restrict__ cnt,
                        int* __restrict__ rank, int E) {
    int e = blockIdx.x * blockDim.x + threadIdx.x;
    if (e < E) rank[e] = atomicAdd(&cnt[ei[E + e]], 1);
}

__global__ void k_scan1(const int* __restrict__ cnt, int* __restrict__ row,
                        int* __restrict__ bsum, int n) {
    __shared__ int s[256];
    int i = blockIdx.x * 256 + threadIdx.x;
    int v = (i < n) ? cnt[i] : 0;
    s[threadIdx.x] = v;
    __syncthreads();
    for (int off = 1; off < 256; off <<= 1) {
        int tv = (threadIdx.x >= off) ? s[threadIdx.x - off] : 0;
        __syncthreads();
        if (threadIdx.x >= off) s[threadIdx.x] += tv;
        __syncthreads();
    }
    if (i < n) row[i] = s[threadIdx.x] - v;   // exclusive
    if (threadIdx.x == 255) bsum[blockIdx.x] = s[255];
}

__global__ void k_scan2(int* __restrict__ bsum, int nb) {
    __shared__ int s[512];
    int v = (threadIdx.x < nb) ? bsum[threadIdx.x] : 0;
    s[threadIdx.x] = v;
    __syncthreads();
    for (int off = 1; off < 512; off <<= 1) {
        int tv = (threadIdx.x >= off) ? s[threadIdx.x - off] : 0;
        __syncthreads();
        if (threadIdx.x >= off) s[threadIdx.x] += tv;
        __syncthreads();
    }
    if (threadIdx.x < nb) bsum[threadIdx.x] = s[threadIdx.x] - v;  // exclusive
}

__global__ void k_scan3(int* __restrict__ row, const int* __restrict__ bsum,
                        int n, int E) {
    int i = blockIdx.x * blockDim.x + threadIdx.x;
    if (i < n) row[i] = row[i] + bsum[i >> 8];
    if (i == 0) row[n] = E;
}

// pos = row[dest] + rank  (no atomics); one packed 8B store per edge
__global__ void k_fill(const int* __restrict__ ei, const float* __restrict__ ew,
                       const int* __restrict__ row, const int* __restrict__ rank,
                       int2* __restrict__ csr, int E) {
    int e = blockIdx.x * blockDim.x + threadIdx.x;
    if (e >= E) return;
    int c = ei[E + e];
    int pos = row[c] + rank[e];
    int2 ent;
    ent.x = ei[e];
    ent.y = __float_as_int(ew[e]);
    csr[pos] = ent;
}

__global__ void k_dinv(const int* __restrict__ row, const int2* __restrict__ csr,
                       float* __restrict__ dinv, int n) {
    int i = blockIdx.x * blockDim.x + threadIdx.x;
    if (i >= n) return;
    int s0 = row[i], s1 = row[i + 1];
    float d = 1.0f;  // self-loop
    for (int s = s0; s < s1; ++s) d += __int_as_float(csr[s].y);
    dinv[i] = rsqrtf(d);
}

// agg9 gather + conv1 + lrelu + conv2 -> t[i][16]; store nrm to wnrm[].
__global__ void k_pass1(const int* __restrict__ row, const int2* __restrict__ csr,
                        float* __restrict__ wnrm, const float* __restrict__ dinv,
                        const float* __restrict__ x, const float* __restrict__ senc,
                        const float* __restrict__ W1, const float* __restrict__ b1,
                        const float* __restrict__ W2, float* __restrict__ t, int n) {
    __shared__ float sW1[288];
    __shared__ float sb1[32];
    __shared__ float sW2[512];
    for (int k = threadIdx.x; k < 288; k += blockDim.x) sW1[k] = W1[k];
    for (int k = threadIdx.x; k < 512; k += blockDim.x) sW2[k] = W2[k];
    if (threadIdx.x < 32) sb1[threadIdx.x] = b1[threadIdx.x];
    __syncthreads();
    int i = blockIdx.x * blockDim.x + threadIdx.x;
    if (i >= n) return;
    float di = dinv[i];
    float d2 = di * di;
    float se = senc[0];
    float a[8];
    const float4* xi = reinterpret_cast<const float4*>(x + (size_t)i * 8);
    float4 u = xi[0], v = xi[1];
    a[0] = d2 * u.x; a[1] = d2 * u.y; a[2] = d2 * u.z; a[3] = d2 * u.w;
    a[4] = d2 * v.x; a[5] = d2 * v.y; a[6] = d2 * v.z; a[7] = d2 * v.w;
    float wsum = d2;  // coefficient of the constant senc column
    int s0 = row[i], s1 = row[i + 1];
    for (int s = s0; s < s1; ++s) {
        int2 ent = csr[s];
        int r = ent.x;
        float nrm = dinv[r] * __int_as_float(ent.y) * di;
        wnrm[s] = nrm;  // reused in pass2
        const float4* xr = reinterpret_cast<const float4*>(x + (size_t)r * 8);
        float4 p = xr[0], q = xr[1];
        a[0] += nrm * p.x; a[1] += nrm * p.y; a[2] += nrm * p.z; a[3] += nrm * p.w;
        a[4] += nrm * q.x; a[5] += nrm * q.y; a[6] += nrm * q.z; a[7] += nrm * q.w;
        wsum += nrm;
    }
    float a8 = wsum * se;
    float h[32];
    #pragma unroll
    for (int j = 0; j < 32; ++j) {
        float acc = sb1[j] + a8 * sW1[8 * 32 + j];
        #pragma unroll
        for (int k = 0; k < 8; ++k) acc += a[k] * sW1[k * 32 + j];
        h[j] = acc > 0.f ? acc : 0.01f * acc;
    }
    float* ti = t + (size_t)i * 16;
    #pragma unroll
    for (int q2 = 0; q2 < 16; ++q2) {
        float acc = 0.f;
        #pragma unroll
        for (int j = 0; j < 32; ++j) acc += h[j] * sW2[j * 16 + q2];
        ti[q2] = acc;
    }
}

// agg16 gather + b2 + lrelu + fc -> out
__global__ void k_pass2(const int* __restrict__ row, const int2* __restrict__ csr,
                        const float* __restrict__ wnrm, const float* __restrict__ dinv,
                        const float* __restrict__ t, const float* __restrict__ b2,
                        const float* __restrict__ fw, const float* __restrict__ fb,
                        float* __restrict__ out, int n) {
    __shared__ float sb2[16];
    __shared__ float sfw[16];
    if (threadIdx.x < 16) { sb2[threadIdx.x] = b2[threadIdx.x]; sfw[threadIdx.x] = fw[threadIdx.x]; }
    __syncthreads();
    int i = blockIdx.x * blockDim.x + threadIdx.x;
    if (i >= n) return;
    float di = dinv[i];
    float d2 = di * di;
    float acc[16];
    const float4* ti = reinterpret_cast<const float4*>(t + (size_t)i * 16);
    #pragma unroll
    for (int q = 0; q < 4; ++q) {
        float4 u = ti[q];
        acc[4 * q + 0] = d2 * u.x; acc[4 * q + 1] = d2 * u.y;
        acc[4 * q + 2] = d2 * u.z; acc[4 * q + 3] = d2 * u.w;
    }
    int s0 = row[i], s1 = row[i + 1];
    for (int s = s0; s < s1; ++s) {
        int r = csr[s].x;
        float nrm = wnrm[s];
        const float4* tr = reinterpret_cast<const float4*>(t + (size_t)r * 16);
        #pragma unroll
        for (int q = 0; q < 4; ++q) {
            float4 u = tr[q];
            acc[4 * q + 0] += nrm * u.x; acc[4 * q + 1] += nrm * u.y;
            acc[4 * q + 2] += nrm * u.z; acc[4 * q + 3] += nrm * u.w;
        }
    }
    float o = fb[0];
    #pragma unroll
    for (int k = 0; k < 16; ++k) {
        float v = acc[k] + sb2[k];
        v = v > 0.f ? v : 0.01f * v;
        o += v * sfw[k];
    }
    out[i] = o;
}

extern "C" void kernel_launch(void* const* d_in, const int* in_sizes, int n_in,
                              void* d_out, int out_size, void* d_ws, size_t ws_size,
                              hipStream_t stream) {
    const float* x      = (const float*)d_in[0];
    const int*   ei     = (const int*)d_in[1];
    const float* ew     = (const float*)d_in[2];
    const float* sv     = (const float*)d_in[3];
    const float* sfc1w  = (const float*)d_in[4];
    const float* sfc1b  = (const float*)d_in[5];
    const float* sfc2w  = (const float*)d_in[6];
    const float* sfc2b  = (const float*)d_in[7];
    const float* conv1w = (const float*)d_in[8];
    const float* conv1b = (const float*)d_in[9];
    const float* conv2w = (const float*)d_in[10];
    const float* conv2b = (const float*)d_in[11];
    const float* fc1w   = (const float*)d_in[12];
    const float* fc1b   = (const float*)d_in[13];

    const int n = in_sizes[0] / 8;
    const int E = in_sizes[2];

    // workspace layout (4-byte words, each segment aligned to 16B)
    size_t off = 0;
    auto alloc = [&](size_t words) { size_t o = off; off += (words + 3) & ~(size_t)3; return o; };
    float* base   = (float*)d_ws;
    float* senc   = base + alloc(4);
    float* dinv   = base + alloc(n);
    int*   rowp   = (int*)(base + alloc(n + 1));
    int*   cnt    = (int*)(base + alloc(n));
    int*   bsum   = (int*)(base + alloc(1024));
    int*   rank   = (int*)(base + alloc(E));
    int2*  csr    = (int2*)(base + alloc((size_t)2 * E));
    float* wnrm   = base + alloc(E);
    float* tbuf   = base + alloc((size_t)16 * n);

    const int BT = 256;
    const int gN = (n + BT - 1) / BT;
    const int gE = (E + BT - 1) / BT;
    const int nb = gN;  // scan1 blocks (<= 512)

    k_senc<<<1, 64, 0, stream>>>(sv, sfc1w, sfc1b, sfc2w, sfc2b, senc);
    hipMemsetAsync(cnt, 0, (size_t)n * 4, stream);
    k_count<<<gE, BT, 0, stream>>>(ei, cnt, rank, E);
    k_scan1<<<nb, 256, 0, stream>>>(cnt, rowp, bsum, n);
    k_scan2<<<1, 512, 0, stream>>>(bsum, nb);
    k_scan3<<<gN, BT, 0, stream>>>(rowp, bsum, n, E);
    k_fill<<<gE, BT, 0, stream>>>(ei, ew, rowp, rank, csr, E);
    k_dinv<<<gN, BT, 0, stream>>>(rowp, csr, dinv, n);
    k_pass1<<<gN, BT, 0, stream>>>(rowp, csr, wnrm, dinv, x, senc,
                                   conv1w, conv1b, conv2w, tbuf, n);
    k_pass2<<<gN, BT, 0, stream>>>(rowp, csr, wnrm, dinv, tbuf,
                                   conv2b, fc1w, fc1b, (float*)d_out, n);
}